// Round 2
// baseline (237.075 us; speedup 1.0000x reference)
//
#include <hip/hip_runtime.h>
#include <hip/hip_bf16.h>

typedef __attribute__((ext_vector_type(8))) __bf16 bf16x8;
typedef __attribute__((ext_vector_type(4))) __bf16 bf16x4;
typedef __attribute__((ext_vector_type(4))) float  f32x4;

namespace {
constexpr int kB  = 16;
constexpr int kSQ = 2048;
constexpr int kSK = 2048;
constexpr int kD  = 64;
constexpr int kQB = 16;               // q-rows per workgroup
constexpr int kNW = 8;                // waves per workgroup
constexpr int kLdsP = kQB * kSK * 2;  // 65536 B (P tile, bf16, swizzled)
constexpr int kLdsTot = kLdsP + kNW * kQB * 4; // + row-sum partials = 66048 B
constexpr float kScaleLog2e = 0.18033688011112042f; // (1/8)*log2(e)
}

// One wg = (batch b, 16 q-rows), 8 waves, 66 KB LDS -> 2 wgs/CU.
// Pass 1: S=QK^T via 16x16x32 bf16 MFMA, mask, exp2, unnormalized P -> swizzled
// LDS (bf16) + per-row sums. Pass 2a: attn = P/l coalesced f32 writes.
// Pass 2b: PV via MFMA (A from LDS, B=V from L2), cross-wave reduce in LDS
// (reusing P region), scale by 1/l, write ctx.
__global__ __launch_bounds__(512, 4)
void sdpa_fused(const float* __restrict__ Qg, const float* __restrict__ Kg,
                const float* __restrict__ Vg, const int* __restrict__ Mg,
                float* __restrict__ ctxOut, float* __restrict__ attnOut)
{
  __shared__ __align__(16) char lds[kLdsTot];
  float* sums  = reinterpret_cast<float*>(lds + kLdsP); // [8][16] row-sum partials
  float* cpart = reinterpret_cast<float*>(lds);         // reuse of P region later

  const int tid  = threadIdx.x;
  const int wid  = tid >> 6;
  const int lane = tid & 63;
  const int l15  = lane & 15;
  const int kg   = lane >> 4;        // 0..3 (k-group / row-group)

  // XCD-aware bijective swizzle: 2048 wgs, 256 contiguous per XCD (2 batches).
  const int wg = (blockIdx.x & 7) * 256 + (blockIdx.x >> 3);
  const int b  = wg >> 7;            // 128 q-blocks per batch
  const int q0 = (wg & 127) * kQB;

  const float* Qb = Qg + (size_t)b * kSQ * kD;
  const float* Kb = Kg + (size_t)b * kSK * kD;
  const float* Vb = Vg + (size_t)b * kSK * kD;
  const int*   Mb = Mg + (size_t)b * kSQ * kSK;

  // ---- Q fragments (A of 16x16x32: row = lane&15, k = (lane>>4)*8+e) ----
  bf16x8 qf[2];
  {
    const float* qp = Qb + (q0 + l15) * kD + kg * 8;
#pragma unroll
    for (int s = 0; s < 2; ++s)
#pragma unroll
      for (int e = 0; e < 8; ++e) qf[s][e] = (__bf16)qp[s * 32 + e];
  }

  // ---- pass 1: each wave owns 256 keys = 16 tiles of 16 ----
  float lsum[4] = {0.f, 0.f, 0.f, 0.f};
  for (int kt = 0; kt < 16; ++kt) {
    const int k0 = wid * 256 + kt * 16;
    f32x4 acc = {0.f, 0.f, 0.f, 0.f};
    const float* kp = Kb + (size_t)(k0 + l15) * kD + kg * 8;
#pragma unroll
    for (int s = 0; s < 2; ++s) {
      bf16x8 kf;
#pragma unroll
      for (int e = 0; e < 8; ++e) kf[e] = (__bf16)kp[s * 32 + e];
      acc = __builtin_amdgcn_mfma_f32_16x16x32_bf16(qf[s], kf, acc, 0, 0, 0);
    }
    // C/D layout: col = lane&15, row = (lane>>4)*4 + r
    const int col = k0 + l15;
    const int* mp = Mb + (size_t)(q0 + kg * 4) * kSK + col;
#pragma unroll
    for (int r = 0; r < 4; ++r) {
      const int row = kg * 4 + r;
      const int mv  = mp[(size_t)r * kSK];           // mask TRUE -> excluded
      const float pv =
          mv ? 0.f : __builtin_amdgcn_exp2f(acc[r] * kScaleLog2e);
      lsum[r] += pv;
      const int byte = ((row << 12) + (col << 1)) ^ ((row & 7) << 4); // swizzle
      *reinterpret_cast<__bf16*>(lds + byte) = (__bf16)pv;
    }
  }

  // ---- row-sum reduction within each 16-lane group (disjoint rows) ----
#pragma unroll
  for (int m = 1; m < 16; m <<= 1)
#pragma unroll
    for (int r = 0; r < 4; ++r) lsum[r] += __shfl_xor(lsum[r], m, 64);
  if (l15 == 0) {
#pragma unroll
    for (int r = 0; r < 4; ++r) sums[wid * kQB + kg * 4 + r] = lsum[r];
  }
  __syncthreads();

  // ---- pass 2a: attn = P / l (wave owns 2 q-rows, coalesced f32x4 stores)
#pragma unroll
  for (int rr = 0; rr < 2; ++rr) {
    const int row = wid * 2 + rr;
    float l = 0.f;
#pragma unroll
    for (int w = 0; w < kNW; ++w) l += sums[w * kQB + row];
    const float inv = 1.0f / l;
    const int xorm = (row & 7) << 4;
    float* arow = attnOut + ((size_t)b * kSQ + q0 + row) * kSK;
    for (int c0 = lane * 4; c0 < kSK; c0 += 256) {
      const int byte = ((row << 12) + (c0 << 1)) ^ xorm;
      const bf16x4 p4 = *reinterpret_cast<const bf16x4*>(lds + byte);
      float4 o;
      o.x = (float)p4[0] * inv;
      o.y = (float)p4[1] * inv;
      o.z = (float)p4[2] * inv;
      o.w = (float)p4[3] * inv;
      *reinterpret_cast<float4*>(arow + c0) = o;
    }
  }

  // ---- pass 2b: PV. Each wave owns 256 keys; 4 n-tiles cover d=0..63 ----
  f32x4 cacc[4];
#pragma unroll
  for (int nt = 0; nt < 4; ++nt) cacc[nt] = f32x4{0.f, 0.f, 0.f, 0.f};
  for (int ks = 0; ks < 8; ++ks) {
    const int kk = wid * 256 + ks * 32;
    // A-frag: row = l15 (q row), k = kk + kg*8 + e  (from swizzled LDS)
    const int abyte = ((l15 << 12) + ((kk + kg * 8) << 1)) ^ ((l15 & 7) << 4);
    const bf16x8 af = *reinterpret_cast<const bf16x8*>(lds + abyte);
#pragma unroll
    for (int nt = 0; nt < 4; ++nt) {
      bf16x8 vf;  // B: col = lane&15 (=d), k = (lane>>4)*8+e
      const float* vp = Vb + (size_t)(kk + kg * 8) * kD + nt * 16 + l15;
#pragma unroll
      for (int e = 0; e < 8; ++e) vf[e] = (__bf16)vp[e * kD];
      cacc[nt] = __builtin_amdgcn_mfma_f32_16x16x32_bf16(af, vf, cacc[nt], 0, 0, 0);
    }
  }
  __syncthreads();  // all P reads done; P region reused for ctx partials

#pragma unroll
  for (int nt = 0; nt < 4; ++nt)
#pragma unroll
    for (int r = 0; r < 4; ++r)
      cpart[wid * (kQB * kD) + (kg * 4 + r) * kD + nt * 16 + l15] = cacc[nt][r];
  __syncthreads();

  // ---- final: reduce 8 partials, scale by 1/l, write ctx ----
  if (tid < kQB * 16) {
    const int row = tid >> 4;
    const int c   = (tid & 15) * 4;
    float4 o = make_float4(0.f, 0.f, 0.f, 0.f);
#pragma unroll
    for (int w = 0; w < kNW; ++w) {
      const float4 pv = *reinterpret_cast<const float4*>(
          cpart + w * (kQB * kD) + row * kD + c);
      o.x += pv.x; o.y += pv.y; o.z += pv.z; o.w += pv.w;
    }
    float l = 0.f;
#pragma unroll
    for (int w = 0; w < kNW; ++w) l += sums[w * kQB + row];
    const float inv = 1.0f / l;
    o.x *= inv; o.y *= inv; o.z *= inv; o.w *= inv;
    *reinterpret_cast<float4*>(ctxOut + ((size_t)b * kSQ + q0 + row) * kD + c) = o;
  }
}

extern "C" void kernel_launch(void* const* d_in, const int* in_sizes, int n_in,
                              void* d_out, int out_size, void* d_ws, size_t ws_size,
                              hipStream_t stream)
{
  const float* Q = (const float*)d_in[0];
  const float* K = (const float*)d_in[1];
  const float* V = (const float*)d_in[2];
  const int*   M = (const int*)d_in[3];   // bool mask pushed as 4-byte words
  float* ctx  = (float*)d_out;
  float* attn = (float*)d_out + (size_t)kB * kSQ * kD;

  dim3 grid(kB * (kSQ / kQB));  // 2048
  dim3 block(512);
  hipLaunchKernelGGL(sdpa_fused, grid, block, 0, stream, Q, K, V, M, ctx, attn);
}